// Round 2
// baseline (107.760 us; speedup 1.0000x reference)
//
#include <hip/hip_runtime.h>
#include <hip/hip_bf16.h>

// VoxelNeRF Raw2Alpha + Alphas2Weights (segmented exclusive scan in log space).
//
// Inputs (f32 unless noted): density[M], ray_id[M] (int32, sorted), shift[1],
// interval[1], N[1] (int). Outputs concatenated in d_out: weights[M] f32,
// alphainv_last[N] f32.
//
// Structure:
//   k1: segment start offsets from sorted ray_id -> start[N+1] in d_ws
//   k2: one 64-lane wave per ray; chunked wave-scan of lom with scalar carry.

__global__ void VoxelNeRF_find_starts(const int* __restrict__ ray_id,
                                      int* __restrict__ start,
                                      int M, int N) {
    int i = blockIdx.x * blockDim.x + threadIdx.x;
    if (i >= M) return;
    int cur  = ray_id[i];
    int prev = (i == 0) ? -1 : ray_id[i - 1];
    // boundary: rays (prev, cur] begin at i  (handles empty rays)
    for (int r = prev + 1; r <= cur; ++r) start[r] = i;
    if (i == M - 1) {
        for (int r = cur + 1; r <= N; ++r) start[r] = M;
    }
}

__global__ __launch_bounds__(256) void VoxelNeRF_scan(
    const float* __restrict__ density,
    const int*   __restrict__ start,
    const float* __restrict__ shift_p,
    const float* __restrict__ interval_p,
    float* __restrict__ weights,
    float* __restrict__ alphainv_last,
    int N) {
    const int wave = threadIdx.x >> 6;
    const int lane = threadIdx.x & 63;
    const int r = blockIdx.x * 4 + wave;
    if (r >= N) return;

    const int s = start[r];
    const int e = start[r + 1];
    const float shift    = shift_p[0];
    const float interval = interval_p[0];

    float carry = 0.0f;  // inclusive sum of lom over all previous chunks of this ray

    for (int base = s; base < e; base += 64) {
        const int i = base + lane;
        float lom = 0.0f;   // log(1 - alpha) <= 0
        float alpha = 0.0f;
        if (i < e) {
            const float x  = density[i] + shift;
            // stable softplus
            const float sp = fmaxf(x, 0.0f) + log1pf(expf(-fabsf(x)));
            lom   = -sp * interval;
            alpha = -expm1f(lom);
        }
        // inclusive wave scan of lom
        float v = lom;
        #pragma unroll
        for (int off = 1; off < 64; off <<= 1) {
            float t = __shfl_up(v, off, 64);
            if (lane >= off) v += t;
        }
        const float ex = carry + (v - lom);  // exclusive per-ray cumsum
        if (i < e) {
            weights[i] = expf(ex) * alpha;
        }
        carry += __shfl(v, 63, 64);  // chunk total
    }

    if (lane == 0) {
        alphainv_last[r] = expf(carry);
    }
}

extern "C" void kernel_launch(void* const* d_in, const int* in_sizes, int n_in,
                              void* d_out, int out_size, void* d_ws, size_t ws_size,
                              hipStream_t stream) {
    const float* density    = (const float*)d_in[0];
    const int*   ray_id     = (const int*)d_in[1];
    const float* shift_p    = (const float*)d_in[2];
    const float* interval_p = (const float*)d_in[3];
    // d_in[4] is N as a 1-element device array; derive N without device reads:
    const int M = in_sizes[0];
    const int N = out_size - M;

    float* weights       = (float*)d_out;
    float* alphainv_last = (float*)d_out + M;
    int*   start         = (int*)d_ws;   // N+1 ints

    {
        const int threads = 256;
        const int blocks  = (M + threads - 1) / threads;
        VoxelNeRF_find_starts<<<blocks, threads, 0, stream>>>(ray_id, start, M, N);
    }
    {
        const int waves_per_block = 4;
        const int blocks = (N + waves_per_block - 1) / waves_per_block;
        VoxelNeRF_scan<<<blocks, 256, 0, stream>>>(
            density, start, shift_p, interval_p, weights, alphainv_last, N);
    }
}

// Round 3
// 95.536 us; speedup vs baseline: 1.1280x; 1.1280x over previous
//
#include <hip/hip_runtime.h>
#include <hip/hip_bf16.h>

// VoxelNeRF Raw2Alpha + Alphas2Weights (segmented exclusive scan in log space).
//
// k1 (find_starts): segment offsets start[N+1] from sorted ray_id (int4-vectorized).
// k2 (scan): one wave per ray. Lane j owns 6 consecutive elements; per-lane
//            serial prefix + ONE wave-level DPP scan per 384-element chunk
//            (max ray len ~336 for this distribution => 1 iteration typical).
//            DPP scan = row_shr 1/2/4/8 + row_bcast 15/31, pure VALU, no LDS.

#define ELEMS_PER_LANE 6
#define CHUNK (64 * ELEMS_PER_LANE)

__device__ __forceinline__ float wave_incl_scan(float x) {
    // inclusive add-scan across 64 lanes via DPP (GCN/CDNA row ops)
    float v = x;
    v += __int_as_float(__builtin_amdgcn_update_dpp(0, __float_as_int(v), 0x111, 0xf, 0xf, true));  // row_shr:1
    v += __int_as_float(__builtin_amdgcn_update_dpp(0, __float_as_int(v), 0x112, 0xf, 0xf, true));  // row_shr:2
    v += __int_as_float(__builtin_amdgcn_update_dpp(0, __float_as_int(v), 0x114, 0xf, 0xf, true));  // row_shr:4
    v += __int_as_float(__builtin_amdgcn_update_dpp(0, __float_as_int(v), 0x118, 0xf, 0xf, true));  // row_shr:8
    v += __int_as_float(__builtin_amdgcn_update_dpp(0, __float_as_int(v), 0x142, 0xa, 0xf, false)); // row_bcast:15 -> rows 1,3
    v += __int_as_float(__builtin_amdgcn_update_dpp(0, __float_as_int(v), 0x143, 0xc, 0xf, false)); // row_bcast:31 -> rows 2,3
    return v;
}

__global__ void VoxelNeRF_find_starts(const int* __restrict__ ray_id,
                                      int* __restrict__ start,
                                      int M, int N) {
    const int j  = blockIdx.x * blockDim.x + threadIdx.x;
    const int i0 = j * 4;
    if (i0 >= M) return;
    const int4 v = *reinterpret_cast<const int4*>(ray_id + i0);  // M % 4 == 0, 16B-aligned
    int prev = (i0 == 0) ? -1 : ray_id[i0 - 1];
    const int ids0 = v.x, ids1 = v.y, ids2 = v.z, ids3 = v.w;
    #pragma unroll
    for (int k = 0; k < 4; ++k) {
        const int cur = (k == 0) ? ids0 : (k == 1) ? ids1 : (k == 2) ? ids2 : ids3;
        if (cur != prev) {
            for (int r = prev + 1; r <= cur; ++r) start[r] = i0 + k;
        }
        prev = cur;
    }
    if (i0 + 4 >= M) {
        for (int r = prev + 1; r <= N; ++r) start[r] = M;
    }
}

__global__ __launch_bounds__(256) void VoxelNeRF_scan(
    const float* __restrict__ density,
    const int*   __restrict__ start,
    const float* __restrict__ shift_p,
    const float* __restrict__ interval_p,
    float* __restrict__ weights,
    float* __restrict__ alphainv_last,
    int N) {
    const int wave = threadIdx.x >> 6;
    const int lane = threadIdx.x & 63;
    const int r = blockIdx.x * 4 + wave;
    if (r >= N) return;

    const int s = start[r];
    const int e = start[r + 1];
    const float shift    = shift_p[0];
    const float interval = interval_p[0];

    float carry = 0.0f;  // sum of lom over previous chunks of this ray

    for (int base = s; base < e; base += CHUNK) {
        const int i0 = base + lane * ELEMS_PER_LANE;

        float lm[ELEMS_PER_LANE];   // log(1-alpha), <= 0 (0 for out-of-segment)
        float al[ELEMS_PER_LANE];   // alpha
        float pk[ELEMS_PER_LANE];   // exclusive prefix within lane
        float lane_sum = 0.0f;

        #pragma unroll
        for (int k = 0; k < ELEMS_PER_LANE; ++k) {
            const int i = i0 + k;
            float lomk = 0.0f, alk = 0.0f;
            if (i < e) {
                const float x  = density[i] + shift;
                // stable softplus with fast intrinsics (abs err ~1e-7)
                const float sp = fmaxf(x, 0.0f) + __logf(1.0f + __expf(-fabsf(x)));
                lomk = -sp * interval;
                alk  = 1.0f - __expf(lomk);
            }
            lm[k] = lomk;
            al[k] = alk;
            pk[k] = lane_sum;      // exclusive-within-lane prefix
            lane_sum += lomk;
        }

        // inclusive scan of per-lane sums across the wave (pure-VALU DPP)
        const float v_incl = wave_incl_scan(lane_sum);
        const float excl_lane = carry + (v_incl - lane_sum);  // exclusive per-lane base

        #pragma unroll
        for (int k = 0; k < ELEMS_PER_LANE; ++k) {
            const int i = i0 + k;
            if (i < e) {
                weights[i] = __expf(excl_lane + pk[k]) * al[k];
            }
        }

        // chunk total = inclusive value at lane 63 (broadcast via readlane)
        carry += __int_as_float(__builtin_amdgcn_readlane(__float_as_int(v_incl), 63));
    }

    if (lane == 0) {
        alphainv_last[r] = __expf(carry);
    }
}

extern "C" void kernel_launch(void* const* d_in, const int* in_sizes, int n_in,
                              void* d_out, int out_size, void* d_ws, size_t ws_size,
                              hipStream_t stream) {
    const float* density    = (const float*)d_in[0];
    const int*   ray_id     = (const int*)d_in[1];
    const float* shift_p    = (const float*)d_in[2];
    const float* interval_p = (const float*)d_in[3];
    const int M = in_sizes[0];
    const int N = out_size - M;

    float* weights       = (float*)d_out;
    float* alphainv_last = (float*)d_out + M;
    int*   start         = (int*)d_ws;   // N+1 ints

    {
        const int threads = 256;
        const int elems   = (M + 3) / 4;
        const int blocks  = (elems + threads - 1) / threads;
        VoxelNeRF_find_starts<<<blocks, threads, 0, stream>>>(ray_id, start, M, N);
    }
    {
        const int waves_per_block = 4;
        const int blocks = (N + waves_per_block - 1) / waves_per_block;
        VoxelNeRF_scan<<<blocks, 256, 0, stream>>>(
            density, start, shift_p, interval_p, weights, alphainv_last, N);
    }
}